// Round 3
// baseline (28.303 us; speedup 1.0000x reference)
//
#include <hip/hip_runtime.h>

typedef int int4v __attribute__((ext_vector_type(4)));

// 4 int4 per thread, region-strided, loads issued before any use (MLP).
//  blocks [0, tok_blocks)               : tokens -> pad-replace -> count-mask -> out
//  blocks [tok_blocks, tok_blocks+cb)   : counts passthrough copy
__global__ __launch_bounds__(256) void FusedSpeculativeBase_kernel(
    const int* __restrict__ tokens,   // [B*K] int32
    const int* __restrict__ counts,   // [B]   int32
    const int* __restrict__ pad_ptr,  // [1]   int32
    int* __restrict__ out,            // [B*K + B] int32
    int n_tok_vec,                    // B*K/4
    int n_cnt_vec,                    // B/4
    int tok_blocks,                   // blocks covering token region
    int tok_threads,                  // tok_blocks*256 (stride between a thread's 4 vecs)
    int cnt_threads,                  // cnt_blocks*256
    int row_shift)                    // log2(K/4)
{
    if (blockIdx.x < (unsigned)tok_blocks) {
        const int tid = blockIdx.x * 256 + threadIdx.x;
        const int pad = pad_ptr[0];
        const int npv = tokens[0];                        // value at [0,0], pre-replacement

        int   idx[4];
        bool  ok[4];
        int4v v[4];
        int   cnt[4];
#pragma unroll
        for (int t = 0; t < 4; ++t) {
            idx[t] = tid + t * tok_threads;
            ok[t]  = idx[t] < n_tok_vec;
            if (ok[t]) v[t] = __builtin_nontemporal_load((const int4v*)tokens + idx[t]);
        }
#pragma unroll
        for (int t = 0; t < 4; ++t) {
            if (ok[t]) cnt[t] = counts[idx[t] >> row_shift];
        }
#pragma unroll
        for (int t = 0; t < 4; ++t) {
            if (!ok[t]) continue;
            const int p0 = (idx[t] & ((1 << row_shift) - 1)) << 2;
            int4v r;
#pragma unroll
            for (int j = 0; j < 4; ++j) {
                int x = v[t][j];
                x = (x == pad) ? npv : x;                 // pad replacement
                r[j] = ((p0 + j) < cnt[t]) ? x : pad;     // keep first cnt tokens
            }
            __builtin_nontemporal_store(r, (int4v*)out + idx[t]);
        }
    } else {
        const int tid = (blockIdx.x - tok_blocks) * 256 + threadIdx.x;
        int4v* out_cnt = (int4v*)(out + ((size_t)n_tok_vec << 2));
#pragma unroll
        for (int t = 0; t < 4; ++t) {
            const int c = tid + t * cnt_threads;
            if (c < n_cnt_vec) {
                const int4v cv = __builtin_nontemporal_load((const int4v*)counts + c);
                __builtin_nontemporal_store(cv, out_cnt + c);
            }
        }
    }
}

extern "C" void kernel_launch(void* const* d_in, const int* in_sizes, int n_in,
                              void* d_out, int out_size, void* d_ws, size_t ws_size,
                              hipStream_t stream) {
    const int* tokens  = (const int*)d_in[0];
    const int* counts  = (const int*)d_in[1];
    const int* pad_ptr = (const int*)d_in[2];
    int* out = (int*)d_out;

    const int n_tok = in_sizes[0];      // B*K
    const int n_b   = in_sizes[1];      // B
    const int K     = n_tok / n_b;      // 64
    const int vecs_per_row = K / 4;     // 16 (power of two)
    int row_shift = 0;
    while ((1 << row_shift) < vecs_per_row) ++row_shift;

    const int n_tok_vec = n_tok / 4;    // 4,194,304
    const int n_cnt_vec = n_b / 4;      // 65,536

    // 4 vec4s per thread
    const int tok_threads_raw = (n_tok_vec + 3) / 4;
    const int tok_blocks  = (tok_threads_raw + 255) / 256;   // 4096
    const int tok_threads = tok_blocks * 256;                // stride
    const int cnt_threads_raw = (n_cnt_vec + 3) / 4;
    const int cnt_blocks  = (cnt_threads_raw + 255) / 256;   // 64
    const int cnt_threads = cnt_blocks * 256;

    FusedSpeculativeBase_kernel<<<tok_blocks + cnt_blocks, 256, 0, stream>>>(
        tokens, counts, pad_ptr, out, n_tok_vec, n_cnt_vec,
        tok_blocks, tok_threads, cnt_threads, row_shift);
}